// Round 1
// baseline (269.437 us; speedup 1.0000x reference)
//
#include <hip/hip_runtime.h>
#include <math.h>

// 2-layer GCN (PyG GCNConv semantics: self-loops + symmetric norm), reduced to
// scalar-per-node form:
//   deg[i]  = indeg(i) + 1 ;  dinv = rsqrt(deg)
//   s[i]    = sum_{e: dst=i} dinv[src]*x[src]  +  dinv[i]*x[i]
//   t[i]    = dinv[i]*s[i]
//   h2[i]   = sum_k sigmoid(W1[k]*t[i] + b1[k]) * W2[k]     (35 terms)
//   r[i]    = sum_{e: dst=i} dinv[src]*h2[src] + dinv[i]*h2[i]
//   out[i]  = sigmoid(dinv[i]*r[i] + b2)

__global__ void k_init_deg(float* __restrict__ deg, int n) {
    int i = blockIdx.x * blockDim.x + threadIdx.x;
    if (i < n) deg[i] = 1.0f;  // self-loop contribution
}

__global__ void k_degree(const int* __restrict__ dst, float* __restrict__ deg, int e) {
    int i = blockIdx.x * blockDim.x + threadIdx.x;
    if (i < e) atomicAdd(&deg[dst[i]], 1.0f);
}

// deg -> dinv (in place); g = dinv*x; s = g (self-loop term pre-added)
__global__ void k_node1(const float* __restrict__ x, float* deg_dinv,
                        float* __restrict__ g, float* __restrict__ s, int n) {
    int i = blockIdx.x * blockDim.x + threadIdx.x;
    if (i < n) {
        float di = rsqrtf(deg_dinv[i]);   // deg >= 1 always (self-loop)
        deg_dinv[i] = di;
        float gi = di * x[i];
        g[i] = gi;
        s[i] = gi;
    }
}

__global__ void k_scatter(const int* __restrict__ src, const int* __restrict__ dst,
                          const float* __restrict__ g, float* __restrict__ s, int e) {
    int i = blockIdx.x * blockDim.x + threadIdx.x;
    if (i < e) atomicAdd(&s[dst[i]], g[src[i]]);
}

// t = dinv*s; h2 = sum_k sigmoid(W1[k]*t+b1[k])*W2[k]; u = dinv*h2; r = u
// NOTE: u aliases g, r aliases s at the call site -> no __restrict__ on those.
__global__ void k_node2(const float* __restrict__ dinv, const float* s,
                        const float* __restrict__ W1, const float* __restrict__ b1,
                        const float* __restrict__ W2,
                        float* u, float* r, int n, int K) {
    int i = blockIdx.x * blockDim.x + threadIdx.x;
    if (i < n) {
        float t = dinv[i] * s[i];
        float h2 = 0.0f;
        for (int k = 0; k < K; ++k) {
            float z = fmaf(W1[k], t, b1[k]);
            float sg = 1.0f / (1.0f + __expf(-z));
            h2 = fmaf(sg, W2[k], h2);
        }
        float ui = dinv[i] * h2;
        u[i] = ui;
        r[i] = ui;
    }
}

__global__ void k_out(const float* __restrict__ dinv, const float* __restrict__ r,
                      const float* __restrict__ b2, float* __restrict__ out, int n) {
    int i = blockIdx.x * blockDim.x + threadIdx.x;
    if (i < n) {
        float z = fmaf(dinv[i], r[i], b2[0]);
        out[i] = 1.0f / (1.0f + __expf(-z));
    }
}

extern "C" void kernel_launch(void* const* d_in, const int* in_sizes, int n_in,
                              void* d_out, int out_size, void* d_ws, size_t ws_size,
                              hipStream_t stream) {
    const float* x  = (const float*)d_in[0];
    const int*   ei = (const int*)d_in[1];   // [2, E] row-major: src then dst
    const float* W1 = (const float*)d_in[2]; // 35
    const float* b1 = (const float*)d_in[3]; // 35
    const float* W2 = (const float*)d_in[4]; // 35
    const float* b2 = (const float*)d_in[5]; // 1

    const int n = in_sizes[0];
    const int e = in_sizes[1] / 2;
    const int K = in_sizes[2];

    const int* src = ei;
    const int* dst = ei + e;

    float* A = (float*)d_ws;   // deg -> dinv
    float* B = A + n;          // g   -> u
    float* C = B + n;          // s   -> r
    float* out = (float*)d_out;

    const int bn = (n + 255) / 256;
    const int be = (e + 255) / 256;

    k_init_deg<<<bn, 256, 0, stream>>>(A, n);
    k_degree  <<<be, 256, 0, stream>>>(dst, A, e);
    k_node1   <<<bn, 256, 0, stream>>>(x, A, B, C, n);
    k_scatter <<<be, 256, 0, stream>>>(src, dst, B, C, e);
    k_node2   <<<bn, 256, 0, stream>>>(A, C, W1, b1, W2, B, C, n, K);
    k_scatter <<<be, 256, 0, stream>>>(src, dst, B, C, e);
    k_out     <<<bn, 256, 0, stream>>>(A, C, b2, out, n);
}

// Round 2
// 156.966 us; speedup vs baseline: 1.7165x; 1.7165x over previous
//
#include <hip/hip_runtime.h>
#include <math.h>

// 2-layer GCN, scalar-per-node form (see round 1), now with a CSR build so the
// graph's 3 uses cost only ONE atomic pass:
//   k_rank   : ranks[e] = atomicAdd(cnt[dst[e]], 1)   (histogram + bucket rank)
//   scanA/B/C: ptr = exclusive_scan(cnt); dinv = rsqrt(1+cnt); g = dinv*x
//   k_reorder: ssrc[ptr[dst]+rank] = src               (plain stores, no atomics)
//   k_layer1 : u[i] = dinv*h2( dinv*(sum_j g[ssrc[j]] + g[i]) )   [gather, no atomics]
//   k_layer2 : out[i] = sigmoid(dinv*(sum_j u[ssrc[j]] + u[i]) + b2)

#define SPAN 2048  // scan: 256 threads * 8 elements per block

__global__ void k_zero(int* __restrict__ cnt, int n) {
    int i = blockIdx.x * 256 + threadIdx.x;
    if (i < n) cnt[i] = 0;
}

// 4 edges per thread (stride-256 unroll keeps loads/stores coalesced, no
// alignment requirement). Atomic returns the within-bucket rank.
__global__ void k_rank(const int* __restrict__ dst, int* __restrict__ cnt,
                       int* __restrict__ ranks, int e) {
    int base = blockIdx.x * 1024 + threadIdx.x;
#pragma unroll
    for (int u = 0; u < 4; ++u) {
        int i = base + u * 256;
        if (i < e) ranks[i] = atomicAdd(&cnt[dst[i]], 1);
    }
}

__global__ void k_scanA(const int* __restrict__ cnt, int* __restrict__ loc,
                        int* __restrict__ bsum, int n) {
    __shared__ int sh[256];
    int t = threadIdx.x;
    int base = blockIdx.x * SPAN + t * 8;
    int v[8];
    int tsum = 0;
#pragma unroll
    for (int j = 0; j < 8; ++j) {
        int idx = base + j;
        int c = (idx < n) ? cnt[idx] : 0;
        v[j] = tsum;          // thread-local exclusive
        tsum += c;
    }
    sh[t] = tsum;
    __syncthreads();
    for (int off = 1; off < 256; off <<= 1) {   // Hillis-Steele inclusive
        int w = (t >= off) ? sh[t - off] : 0;
        __syncthreads();
        sh[t] += w;
        __syncthreads();
    }
    int ex = sh[t] - tsum;    // block-local exclusive offset for this thread
#pragma unroll
    for (int j = 0; j < 8; ++j) {
        int idx = base + j;
        if (idx < n) loc[idx] = ex + v[j];
    }
    if (t == 255) bsum[blockIdx.x] = sh[255];
}

__global__ void k_scanB(int* __restrict__ bsum, int nb) {
    if (blockIdx.x == 0 && threadIdx.x == 0) {
        int acc = 0;
        for (int b = 0; b < nb; ++b) { int v = bsum[b]; bsum[b] = acc; acc += v; }
    }
}

// finalize ptr (in place) + node-side precompute: dinv, g
__global__ void k_scanC(int* __restrict__ loc, const int* __restrict__ bofs,
                        const int* __restrict__ cnt, const float* __restrict__ x,
                        float* __restrict__ dinv, float* __restrict__ g,
                        int n, int e) {
    int t = threadIdx.x;
    int base = blockIdx.x * SPAN + t * 8;
    int add = bofs[blockIdx.x];
#pragma unroll
    for (int j = 0; j < 8; ++j) {
        int idx = base + j;
        if (idx < n) {
            loc[idx] += add;
            float di = rsqrtf(1.0f + (float)cnt[idx]);  // deg = indeg + self-loop
            dinv[idx] = di;
            g[idx] = di * x[idx];
        }
    }
    if (blockIdx.x == 0 && t == 0) loc[n] = e;
}

__global__ void k_reorder(const int* __restrict__ src, const int* __restrict__ dst,
                          const int* __restrict__ ranks, const int* __restrict__ ptr,
                          int* __restrict__ ssrc, int e) {
    int base = blockIdx.x * 1024 + threadIdx.x;
#pragma unroll
    for (int u = 0; u < 4; ++u) {
        int i = base + u * 256;
        if (i < e) ssrc[ptr[dst[i]] + ranks[i]] = src[i];
    }
}

// 16 lanes per node: parallel gather + shfl reduce; all 16 lanes redundantly
// compute the 35-term sigmoid mix (cheap), lane 0 writes.
__global__ void k_layer1(const int* __restrict__ ptr, const int* __restrict__ ssrc,
                         const float* __restrict__ g, const float* __restrict__ dinv,
                         const float* __restrict__ W1, const float* __restrict__ b1,
                         const float* __restrict__ W2,
                         float* __restrict__ u, int n, int K) {
    int gt = blockIdx.x * 256 + threadIdx.x;
    int node = gt >> 4;
    int l = gt & 15;
    if (node >= n) return;
    int b = ptr[node], en = ptr[node + 1];
    float sum = 0.f;
    for (int j = b + l; j < en; j += 16) sum += g[ssrc[j]];
#pragma unroll
    for (int off = 8; off; off >>= 1) sum += __shfl_xor(sum, off, 16);
    sum += g[node];                       // self-loop term
    float t = dinv[node] * sum;
    float h2 = 0.f;
    for (int k = 0; k < K; ++k) {
        float z = fmaf(W1[k], t, b1[k]);
        float sg = __fdividef(1.0f, 1.0f + __expf(-z));
        h2 = fmaf(sg, W2[k], h2);
    }
    if (l == 0) u[node] = dinv[node] * h2;
}

__global__ void k_layer2(const int* __restrict__ ptr, const int* __restrict__ ssrc,
                         const float* __restrict__ u, const float* __restrict__ dinv,
                         const float* __restrict__ b2, float* __restrict__ out, int n) {
    int gt = blockIdx.x * 256 + threadIdx.x;
    int node = gt >> 4;
    int l = gt & 15;
    if (node >= n) return;
    int b = ptr[node], en = ptr[node + 1];
    float sum = 0.f;
    for (int j = b + l; j < en; j += 16) sum += u[ssrc[j]];
#pragma unroll
    for (int off = 8; off; off >>= 1) sum += __shfl_xor(sum, off, 16);
    sum += u[node];
    float z = fmaf(dinv[node], sum, b2[0]);
    if (l == 0) out[node] = __fdividef(1.0f, 1.0f + __expf(-z));
}

// ---------------- fallback (round-1 path, needs only 3n floats) ----------------
__global__ void f_init(float* __restrict__ deg, int n) {
    int i = blockIdx.x * 256 + threadIdx.x;
    if (i < n) deg[i] = 1.0f;
}
__global__ void f_degree(const int* __restrict__ dst, float* __restrict__ deg, int e) {
    int i = blockIdx.x * 256 + threadIdx.x;
    if (i < e) atomicAdd(&deg[dst[i]], 1.0f);
}
__global__ void f_node1(const float* __restrict__ x, float* dd,
                        float* __restrict__ g, float* __restrict__ s, int n) {
    int i = blockIdx.x * 256 + threadIdx.x;
    if (i < n) {
        float di = rsqrtf(dd[i]);
        dd[i] = di;
        float gi = di * x[i];
        g[i] = gi; s[i] = gi;
    }
}
__global__ void f_scatter(const int* __restrict__ src, const int* __restrict__ dst,
                          const float* __restrict__ g, float* __restrict__ s, int e) {
    int i = blockIdx.x * 256 + threadIdx.x;
    if (i < e) atomicAdd(&s[dst[i]], g[src[i]]);
}
__global__ void f_node2(const float* __restrict__ dinv, const float* s,
                        const float* __restrict__ W1, const float* __restrict__ b1,
                        const float* __restrict__ W2, float* u, float* r, int n, int K) {
    int i = blockIdx.x * 256 + threadIdx.x;
    if (i < n) {
        float t = dinv[i] * s[i];
        float h2 = 0.f;
        for (int k = 0; k < K; ++k) {
            float z = fmaf(W1[k], t, b1[k]);
            h2 = fmaf(__fdividef(1.0f, 1.0f + __expf(-z)), W2[k], h2);
        }
        float ui = dinv[i] * h2;
        u[i] = ui; r[i] = ui;
    }
}
__global__ void f_out(const float* __restrict__ dinv, const float* __restrict__ r,
                      const float* __restrict__ b2, float* __restrict__ out, int n) {
    int i = blockIdx.x * 256 + threadIdx.x;
    if (i < n) {
        float z = fmaf(dinv[i], r[i], b2[0]);
        out[i] = __fdividef(1.0f, 1.0f + __expf(-z));
    }
}

extern "C" void kernel_launch(void* const* d_in, const int* in_sizes, int n_in,
                              void* d_out, int out_size, void* d_ws, size_t ws_size,
                              hipStream_t stream) {
    const float* x  = (const float*)d_in[0];
    const int*   ei = (const int*)d_in[1];
    const float* W1 = (const float*)d_in[2];
    const float* b1 = (const float*)d_in[3];
    const float* W2 = (const float*)d_in[4];
    const float* b2 = (const float*)d_in[5];

    const int n = in_sizes[0];
    const int e = in_sizes[1] / 2;
    const int K = in_sizes[2];
    const int* src = ei;
    const int* dst = ei + e;
    float* out = (float*)d_out;

    const int bn  = (n + 255) / 256;
    const int be4 = (e + 1023) / 1024;
    const int nb  = (n + SPAN - 1) / SPAN;
    const int n16 = (n * 16 + 255) / 256;

    // workspace layout (ints are 4B): cnt[n] ptr[n+1] bsum[nb] ranks[e] ssrc[e]
    //                                 dinv[n] g[n] u[n]
    size_t need = ((size_t)5 * n + 1 + (size_t)2 * e + nb) * 4;
    if (ws_size >= need) {
        int* cnt   = (int*)d_ws;
        int* ptr   = cnt + n;
        int* bsum  = ptr + n + 1;
        int* ranks = bsum + nb;
        int* ssrc  = ranks + e;
        float* dinv = (float*)(ssrc + e);
        float* g    = dinv + n;
        float* u    = g + n;

        k_zero   <<<bn, 256, 0, stream>>>(cnt, n);
        k_rank   <<<be4, 256, 0, stream>>>(dst, cnt, ranks, e);
        k_scanA  <<<nb, 256, 0, stream>>>(cnt, ptr, bsum, n);
        k_scanB  <<<1, 64, 0, stream>>>(bsum, nb);
        k_scanC  <<<nb, 256, 0, stream>>>(ptr, bsum, cnt, x, dinv, g, n, e);
        k_reorder<<<be4, 256, 0, stream>>>(src, dst, ranks, ptr, ssrc, e);
        k_layer1 <<<n16, 256, 0, stream>>>(ptr, ssrc, g, dinv, W1, b1, W2, u, n, K);
        k_layer2 <<<n16, 256, 0, stream>>>(ptr, ssrc, u, dinv, b2, out, n);
    } else {
        // round-1 fallback: 3 atomic passes, needs 3n floats
        float* A = (float*)d_ws;
        float* B = A + n;
        float* C = B + n;
        const int be = (e + 255) / 256;
        f_init   <<<bn, 256, 0, stream>>>(A, n);
        f_degree <<<be, 256, 0, stream>>>(dst, A, e);
        f_node1  <<<bn, 256, 0, stream>>>(x, A, B, C, n);
        f_scatter<<<be, 256, 0, stream>>>(src, dst, B, C, e);
        f_node2  <<<bn, 256, 0, stream>>>(A, C, W1, b1, W2, B, C, n, K);
        f_scatter<<<be, 256, 0, stream>>>(src, dst, B, C, e);
        f_out    <<<bn, 256, 0, stream>>>(A, C, b2, out, n);
    }
}

// Round 3
// 97.079 us; speedup vs baseline: 2.7754x; 1.6169x over previous
//
#include <hip/hip_runtime.h>
#include <math.h>

// 2-layer GCN, scalar-per-node form, ZERO global atomics.
// Bucket = dst>>8 (256 nodes/bucket, nb = ceil(n/256) buckets).
//   k_hist   : per-edge-block LDS histogram of coarse buckets -> bh[blk][b]
//   k_colscan: per-bucket exclusive prefix over blocks (bh in place) + bucktot
//   k_bscan  : exclusive scan of bucktot -> buckbase[0..nb]
//   k_bin    : re-read edges; pos = buckbase[b]+bh[blk][b]+LDS-rank;
//              packed[pos] = (src<<8)|(dst&255)        (plain stores)
//   k_deg    : per bucket: LDS int hist by low byte -> dinv, g = dinv*x
//   k_l1     : per bucket: LDS float acc of g[src] -> u = dinv*h2(dinv*(acc+g))
//   k_l2     : per bucket: LDS float acc of u[src] -> out = sigmoid(dinv*(acc+u)+b2)

#define NBLK 256   // edge blocks for hist/bin (must match between the two)
#define TB   256

__global__ void k_hist(const int* __restrict__ dst, int* __restrict__ bh,
                       int e, int ec, int nb) {
    extern __shared__ int sh[];
    int blk = blockIdx.x;
    for (int t = threadIdx.x; t < nb; t += TB) sh[t] = 0;
    __syncthreads();
    int start = blk * ec;
    int end = min(e, start + ec);
    for (int i = start + threadIdx.x; i < end; i += TB)
        atomicAdd(&sh[dst[i] >> 8], 1);
    __syncthreads();
    for (int t = threadIdx.x; t < nb; t += TB) bh[blk * nb + t] = sh[t];
}

__global__ void k_colscan(int* __restrict__ bh, int* __restrict__ bucktot, int nb) {
    int b = blockIdx.x * TB + threadIdx.x;
    if (b >= nb) return;
    int run = 0;
    for (int blk = 0; blk < NBLK; ++blk) {
        int c = bh[blk * nb + b];
        bh[blk * nb + b] = run;
        run += c;
    }
    bucktot[b] = run;
}

__global__ void k_bscan(const int* __restrict__ bucktot, int* __restrict__ buckbase, int nb) {
    __shared__ int sh[1024];
    int t = threadIdx.x;
    int v = (t < nb) ? bucktot[t] : 0;
    sh[t] = v;
    __syncthreads();
    for (int off = 1; off < 1024; off <<= 1) {
        int w = (t >= off) ? sh[t - off] : 0;
        __syncthreads();
        sh[t] += w;
        __syncthreads();
    }
    if (t < nb) buckbase[t] = sh[t] - v;   // exclusive
    if (t == 0) buckbase[nb] = sh[1023];   // total = e
}

__global__ void k_bin(const int* __restrict__ src, const int* __restrict__ dst,
                      const int* __restrict__ bh, const int* __restrict__ buckbase,
                      int* __restrict__ packed, int e, int ec, int nb) {
    extern __shared__ int pos[];
    int blk = blockIdx.x;
    for (int t = threadIdx.x; t < nb; t += TB)
        pos[t] = buckbase[t] + bh[blk * nb + t];
    __syncthreads();
    int start = blk * ec;
    int end = min(e, start + ec);
    for (int i = start + threadIdx.x; i < end; i += TB) {
        int d = dst[i];
        int s = src[i];
        int p = atomicAdd(&pos[d >> 8], 1);       // LDS atomic only
        packed[p] = (s << 8) | (d & 255);
    }
}

__global__ void k_deg(const int* __restrict__ packed, const int* __restrict__ buckbase,
                      const float* __restrict__ x, float* __restrict__ dinv,
                      float* __restrict__ g, int n) {
    __shared__ int cnt[256];
    int b = blockIdx.x;
    cnt[threadIdx.x] = 0;
    __syncthreads();
    int s0 = buckbase[b], s1 = buckbase[b + 1];
    for (int j = s0 + threadIdx.x; j < s1; j += TB)
        atomicAdd(&cnt[packed[j] & 255], 1);
    __syncthreads();
    int node = (b << 8) + threadIdx.x;
    if (node < n) {
        float di = rsqrtf(1.0f + (float)cnt[threadIdx.x]);
        dinv[node] = di;
        g[node] = di * x[node];
    }
}

__global__ void k_l1(const int* __restrict__ packed, const int* __restrict__ buckbase,
                     const float* __restrict__ g, const float* __restrict__ dinv,
                     const float* __restrict__ W1, const float* __restrict__ b1,
                     const float* __restrict__ W2, float* __restrict__ u, int n, int K) {
    __shared__ float acc[256];
    int b = blockIdx.x;
    acc[threadIdx.x] = 0.f;
    __syncthreads();
    int s0 = buckbase[b], s1 = buckbase[b + 1];
    for (int j = s0 + threadIdx.x; j < s1; j += TB) {
        int pk = packed[j];
        atomicAdd(&acc[pk & 255], g[pk >> 8]);    // LDS float atomic
    }
    __syncthreads();
    int node = (b << 8) + threadIdx.x;
    if (node < n) {
        float di = dinv[node];
        float t = di * (acc[threadIdx.x] + g[node]);
        float h2 = 0.f;
        for (int k = 0; k < K; ++k) {
            float z = fmaf(W1[k], t, b1[k]);
            h2 = fmaf(__fdividef(1.f, 1.f + __expf(-z)), W2[k], h2);
        }
        u[node] = di * h2;
    }
}

__global__ void k_l2(const int* __restrict__ packed, const int* __restrict__ buckbase,
                     const float* __restrict__ u, const float* __restrict__ dinv,
                     const float* __restrict__ b2, float* __restrict__ out, int n) {
    __shared__ float acc[256];
    int b = blockIdx.x;
    acc[threadIdx.x] = 0.f;
    __syncthreads();
    int s0 = buckbase[b], s1 = buckbase[b + 1];
    for (int j = s0 + threadIdx.x; j < s1; j += TB) {
        int pk = packed[j];
        atomicAdd(&acc[pk & 255], u[pk >> 8]);
    }
    __syncthreads();
    int node = (b << 8) + threadIdx.x;
    if (node < n) {
        float z = fmaf(dinv[node], acc[threadIdx.x] + u[node], b2[0]);
        out[node] = __fdividef(1.f, 1.f + __expf(-z));
    }
}

// ---------------- fallback (round-1 atomic path, 3n floats) ----------------
__global__ void f_init(float* __restrict__ deg, int n) {
    int i = blockIdx.x * 256 + threadIdx.x;
    if (i < n) deg[i] = 1.0f;
}
__global__ void f_degree(const int* __restrict__ dst, float* __restrict__ deg, int e) {
    int i = blockIdx.x * 256 + threadIdx.x;
    if (i < e) atomicAdd(&deg[dst[i]], 1.0f);
}
__global__ void f_node1(const float* __restrict__ x, float* dd,
                        float* __restrict__ g, float* __restrict__ s, int n) {
    int i = blockIdx.x * 256 + threadIdx.x;
    if (i < n) {
        float di = rsqrtf(dd[i]);
        dd[i] = di;
        float gi = di * x[i];
        g[i] = gi; s[i] = gi;
    }
}
__global__ void f_scatter(const int* __restrict__ src, const int* __restrict__ dst,
                          const float* __restrict__ g, float* __restrict__ s, int e) {
    int i = blockIdx.x * 256 + threadIdx.x;
    if (i < e) atomicAdd(&s[dst[i]], g[src[i]]);
}
__global__ void f_node2(const float* __restrict__ dinv, const float* s,
                        const float* __restrict__ W1, const float* __restrict__ b1,
                        const float* __restrict__ W2, float* u, float* r, int n, int K) {
    int i = blockIdx.x * 256 + threadIdx.x;
    if (i < n) {
        float t = dinv[i] * s[i];
        float h2 = 0.f;
        for (int k = 0; k < K; ++k) {
            float z = fmaf(W1[k], t, b1[k]);
            h2 = fmaf(__fdividef(1.f, 1.f + __expf(-z)), W2[k], h2);
        }
        float ui = dinv[i] * h2;
        u[i] = ui; r[i] = ui;
    }
}
__global__ void f_out(const float* __restrict__ dinv, const float* __restrict__ r,
                      const float* __restrict__ b2, float* __restrict__ out, int n) {
    int i = blockIdx.x * 256 + threadIdx.x;
    if (i < n) {
        float z = fmaf(dinv[i], r[i], b2[0]);
        out[i] = __fdividef(1.f, 1.f + __expf(-z));
    }
}

extern "C" void kernel_launch(void* const* d_in, const int* in_sizes, int n_in,
                              void* d_out, int out_size, void* d_ws, size_t ws_size,
                              hipStream_t stream) {
    const float* x  = (const float*)d_in[0];
    const int*   ei = (const int*)d_in[1];
    const float* W1 = (const float*)d_in[2];
    const float* b1 = (const float*)d_in[3];
    const float* W2 = (const float*)d_in[4];
    const float* b2 = (const float*)d_in[5];

    const int n = in_sizes[0];
    const int e = in_sizes[1] / 2;
    const int K = in_sizes[2];
    const int* src = ei;
    const int* dst = ei + e;
    float* out = (float*)d_out;

    const int nb = (n + 255) >> 8;          // coarse buckets
    const int ec = (e + NBLK - 1) / NBLK;   // edges per hist/bin block

    // ws: bh[NBLK*nb] bucktot[nb] buckbase[nb+1] packed[e] dinv[n] g[n] u[n]
    size_t need = ((size_t)NBLK * nb + 2 * nb + 1 + (size_t)e + 3 * (size_t)n) * 4;

    if (nb <= 1024 && n < (1 << 23) && ws_size >= need) {
        int* bh       = (int*)d_ws;
        int* bucktot  = bh + (size_t)NBLK * nb;
        int* buckbase = bucktot + nb;
        int* packed   = buckbase + nb + 1;
        float* dinv   = (float*)(packed + e);
        float* g      = dinv + n;
        float* u      = g + n;

        k_hist   <<<NBLK, TB, nb * 4, stream>>>(dst, bh, e, ec, nb);
        k_colscan<<<(nb + TB - 1) / TB, TB, 0, stream>>>(bh, bucktot, nb);
        k_bscan  <<<1, 1024, 0, stream>>>(bucktot, buckbase, nb);
        k_bin    <<<NBLK, TB, nb * 4, stream>>>(src, dst, bh, buckbase, packed, e, ec, nb);
        k_deg    <<<nb, TB, 0, stream>>>(packed, buckbase, x, dinv, g, n);
        k_l1     <<<nb, TB, 0, stream>>>(packed, buckbase, g, dinv, W1, b1, W2, u, n, K);
        k_l2     <<<nb, TB, 0, stream>>>(packed, buckbase, u, dinv, b2, out, n);
    } else {
        float* A = (float*)d_ws;
        float* B = A + n;
        float* C = B + n;
        const int bn = (n + 255) / 256;
        const int be = (e + 255) / 256;
        f_init   <<<bn, 256, 0, stream>>>(A, n);
        f_degree <<<be, 256, 0, stream>>>(dst, A, e);
        f_node1  <<<bn, 256, 0, stream>>>(x, A, B, C, n);
        f_scatter<<<be, 256, 0, stream>>>(src, dst, B, C, e);
        f_node2  <<<bn, 256, 0, stream>>>(A, C, W1, b1, W2, B, C, n, K);
        f_scatter<<<be, 256, 0, stream>>>(src, dst, B, C, e);
        f_out    <<<bn, 256, 0, stream>>>(A, C, b2, out, n);
    }
}